// Round 12
// baseline (55.433 us; speedup 1.0000x reference)
//
#include <hip/hip_runtime.h>
#include <hip/hip_bf16.h>

#define BB 128      // batch
#define SS 128      // seq len
#define VD 128      // VALUE_DIM
#define CN 64       // CONCEPT_NUM
#define KD 128      // KEY_DIM
#define QN 10000

typedef __attribute__((ext_vector_type(8))) short bf16x8;
typedef __attribute__((ext_vector_type(4))) float f32x4;
typedef __attribute__((ext_vector_type(2))) float f32x2;

__device__ __forceinline__ float bflo(unsigned int u) { return __uint_as_float(u << 16); }
__device__ __forceinline__ float bfhi(unsigned int u) { return __uint_as_float(u & 0xffff0000u); }
__device__ __forceinline__ unsigned short f2bf(float f) {
    unsigned int x = __float_as_uint(f);
    return (unsigned short)((x + 0x7fffu + ((x >> 16) & 1u)) >> 16);
}
__device__ __forceinline__ unsigned int pk2(float lo, float hi) {
    return (unsigned int)f2bf(lo) | ((unsigned int)f2bf(hi) << 16);
}
__device__ __forceinline__ float fast_tanh(float x) {
    float e = __expf(2.0f * x);
    return 1.0f - 2.0f / (e + 1.0f);
}
__device__ __forceinline__ float fast_sig(float x) {
    return 1.0f / (1.0f + __expf(-x));
}
// packed dual-f32 FMA: d = a*b + c
__device__ __forceinline__ f32x2 pk_fma(f32x2 a, f32x2 b, f32x2 c) {
    f32x2 d;
    asm("v_pk_fma_f32 %0, %1, %2, %3" : "=v"(d) : "v"(a), "v"(b), "v"(c));
    return d;
}
// d = c - a*b
__device__ __forceinline__ f32x2 pk_nfma(f32x2 a, f32x2 b, f32x2 c) {
    f32x2 d;
    asm("v_pk_fma_f32 %0, %1, %2, %3 neg_lo:[1,0,0] neg_hi:[1,0,0]"
        : "=v"(d) : "v"(a), "v"(b), "v"(c));
    return d;
}

// ---------------- kernel 1: weight pack (blocks 0..19) + counts (block 20) ----------------
__global__ __launch_bounds__(256) void k_wcnt(
    const float* __restrict__ erase_W, const float* __restrict__ add_W,
    const float* __restrict__ key_W, unsigned short* __restrict__ Bfrag,
    const int* __restrict__ ri, const int* __restrict__ wi, float* __restrict__ sig)
{
    if (blockIdx.x < 20) {
        const int bid = blockIdx.x * 4 + (threadIdx.x >> 6);   // 0..79
        const int l = threadIdx.x & 63;
        const int n = (bid >> 2) * 16 + (l & 15);
        const int k0 = (bid & 3) * 32 + (l >> 4) * 8;
        const float* src;
        if (n < 128)      src = erase_W + (size_t)n * KD + k0;
        else if (n < 256) src = add_W + (size_t)(n - 128) * KD + k0;
        else              src = key_W + (size_t)(n - 256) * KD + k0;
        float4 fa = ((const float4*)src)[0];
        float4 fb = ((const float4*)src)[1];
        uint4 o = make_uint4(pk2(fa.x, fa.y), pk2(fa.z, fa.w), pk2(fb.x, fb.y), pk2(fb.z, fb.w));
        *(uint4*)(Bfrag + ((size_t)bid * 64 + l) * 8) = o;
    } else {
        __shared__ int sr_s[4], sw_s[4];
        const int t = threadIdx.x;
        const int4* r4 = (const int4*)ri;
        const int4* w4 = (const int4*)wi;
        int sr = 0, sw = 0;
        #pragma unroll 4
        for (int p = 0; p < 16; ++p) {
            int4 a = r4[p * 256 + t];
            int4 b = w4[p * 256 + t];
            sr += (a.x >= 1) + (a.y >= 1) + (a.z >= 1) + (a.w >= 1);
            sw += (b.x >= 1) + (b.y >= 1) + (b.z >= 1) + (b.w >= 1);
        }
        for (int off = 1; off < 64; off <<= 1) { sr += __shfl_xor(sr, off); sw += __shfl_xor(sw, off); }
        int wid = t >> 6;
        if ((t & 63) == 0) { sr_s[wid] = sr; sw_s[wid] = sw; }
        __syncthreads();
        if (t == 0) {
            int SR = sr_s[0]+sr_s[1]+sr_s[2]+sr_s[3];
            int SW = sw_s[0]+sw_s[1]+sw_s[2]+sw_s[3];
            sig[0] = 1.0f / (1.0f + __expf(-(float)SR));
            sig[1] = 1.0f / (1.0f + __expf(-(float)SW));
        }
    }
}

// ---------------- kernel 2: fused per-chain, 1024 threads (16 waves), split-s scan ----------------
// grid 256 = chain (m*BB + b).
__global__ __launch_bounds__(1024, 4) void k_chain(
    const int* __restrict__ ri, const int* __restrict__ wi, const int* __restrict__ tgt,
    const float* __restrict__ q_emb, const float* __restrict__ i_emb,
    const float* __restrict__ key_W,
    const float* __restrict__ erase_b, const float* __restrict__ add_b,
    const unsigned short* __restrict__ Bfrag,
    const float* __restrict__ rmem0, const float* __restrict__ wmem0,
    float* __restrict__ readbuf)
{
    __shared__ __align__(16) unsigned int lds_ea[SS * VD];    // 64 KB: {e,a} bf16 pair per u32
    __shared__ __align__(16) char xab[32 * 1024];             // 32 KB: Xq, then Xi (bf16, swizzled)
    __shared__ __align__(16) float logits[SS * 68];           // 34816 B; later m_mid [128][68]
    __shared__ __align__(16) unsigned short lds_w[SS * CN];   // 16 KB: W bf16
    __shared__ float q_t[KD];
    __shared__ float logit_t[CN];
    __shared__ float wt_lds[CN];
    __shared__ int qid_s[SS], ir_s[SS];
    __shared__ float psum[8 * 64];

    const int t = threadIdx.x;
    const int lane = t & 63;
    const int w = t >> 6;              // 0..15
    const int chain = blockIdx.x;
    const int m = chain >> 7;
    const int b = chain & 127;

    // ---- P0: ids + target q row ----
    if (t < SS) {
        int inter = (m == 0 ? ri : wi)[b * SS + t];
        ir_s[t] = inter;
        qid_s[t] = (inter > QN) ? inter - QN : inter;
        q_t[t] = q_emb[(size_t)tgt[b] * KD + t];
    }
    __syncthreads();

    // ---- P1: stage Xq (bf16 swizzled, 1 row-half/thread) + target-logit partial dots ----
    {
        const int r = t >> 3, o = t & 7;
        const float* src = q_emb + (size_t)qid_s[r] * KD + o * 16;
        float4 f0 = ((const float4*)src)[0];
        float4 f1 = ((const float4*)src)[1];
        float4 f2 = ((const float4*)src)[2];
        float4 f3 = ((const float4*)src)[3];
        const int bb = r * 256 + o * 32;
        const int sw = (r & 7) << 4;
        *(uint4*)(xab + (bb ^ sw))        = make_uint4(pk2(f0.x,f0.y), pk2(f0.z,f0.w), pk2(f1.x,f1.y), pk2(f1.z,f1.w));
        *(uint4*)(xab + ((bb + 16) ^ sw)) = make_uint4(pk2(f2.x,f2.y), pk2(f2.z,f2.w), pk2(f3.x,f3.y), pk2(f3.z,f3.w));
        if (t < 512) {
            const int c = t >> 3, oct = t & 7;
            const float* kw = key_W + (size_t)c * KD + oct * 16;
            float s = 0.f;
            #pragma unroll
            for (int i = 0; i < 16; ++i) s = fmaf(kw[i], q_t[oct * 16 + i], s);
            s += __shfl_xor(s, 1); s += __shfl_xor(s, 2); s += __shfl_xor(s, 4);
            if (oct == 0) logit_t[c] = s;
        }
    }
    __syncthreads();

    const int rowl = lane & 15;
    const int kb16 = (lane >> 4) * 16;
    const int rb4 = (lane >> 4) * 4;
    const int rt = w & 7;              // row-tile 0..7

    // ---- P2: W-logits MFMA (wave w: row-tile rt, nt pair (w>>3)*2); wave 0: target softmax ----
    {
        if (w == 0) {
            float x = logit_t[lane];
            float mx = x;
            #pragma unroll
            for (int off = 1; off < 64; off <<= 1) mx = fmaxf(mx, __shfl_xor(mx, off));
            float e = __expf(x - mx);
            float ssum = e;
            #pragma unroll
            for (int off = 1; off < 64; off <<= 1) ssum += __shfl_xor(ssum, off);
            wt_lds[lane] = e / ssum;
        }
        bf16x8 afQ[4];
        const int row = rt * 16 + rowl;
        #pragma unroll
        for (int kt = 0; kt < 4; ++kt)
            afQ[kt] = *(const bf16x8*)(xab + ((row * 256 + kt * 64 + kb16) ^ ((row & 7) << 4)));
        const int nt0 = (w >> 3) * 2;
        #pragma unroll
        for (int ni = 0; ni < 2; ++ni) {
            const int nt = nt0 + ni;
            f32x4 acc = {0.f,0.f,0.f,0.f};
            #pragma unroll
            for (int kt = 0; kt < 4; ++kt) {
                bf16x8 bf = *(const bf16x8*)(Bfrag + ((size_t)((16 + nt) * 4 + kt) * 64 + lane) * 8);
                acc = __builtin_amdgcn_mfma_f32_16x16x32_bf16(afQ[kt], bf, acc, 0, 0, 0);
            }
            #pragma unroll
            for (int rr = 0; rr < 4; ++rr)
                logits[(rt * 16 + rb4 + rr) * 68 + nt * 16 + rowl] = acc[rr];
        }
    }
    __syncthreads();

    // ---- P3: softmax rows -> lds_w (8 thr/row) + stage Xi into xab ----
    {
        const int rr = t >> 3, q = t & 7;
        const float* L = logits + rr * 68 + q * 8;
        float4 va = ((const float4*)L)[0];
        float4 vb = ((const float4*)L)[1];
        float mx = fmaxf(fmaxf(fmaxf(va.x, va.y), fmaxf(va.z, va.w)),
                         fmaxf(fmaxf(vb.x, vb.y), fmaxf(vb.z, vb.w)));
        mx = fmaxf(mx, __shfl_xor(mx, 1));
        mx = fmaxf(mx, __shfl_xor(mx, 2));
        mx = fmaxf(mx, __shfl_xor(mx, 4));
        float e0 = __expf(va.x - mx), e1 = __expf(va.y - mx), e2 = __expf(va.z - mx), e3 = __expf(va.w - mx);
        float e4 = __expf(vb.x - mx), e5 = __expf(vb.y - mx), e6 = __expf(vb.z - mx), e7 = __expf(vb.w - mx);
        float s = e0 + e1 + e2 + e3 + e4 + e5 + e6 + e7;
        s += __shfl_xor(s, 1); s += __shfl_xor(s, 2); s += __shfl_xor(s, 4);
        float inv = 1.0f / s;
        uint4 o = make_uint4(pk2(e0*inv, e1*inv), pk2(e2*inv, e3*inv),
                             pk2(e4*inv, e5*inv), pk2(e6*inv, e7*inv));
        *(uint4*)(lds_w + rr * CN + q * 8) = o;

        // Xi gather (Xq in xab dead after P2's barrier)
        const float* src = i_emb + (size_t)ir_s[rr] * KD + q * 16;
        float4 f0 = ((const float4*)src)[0];
        float4 f1 = ((const float4*)src)[1];
        float4 f2 = ((const float4*)src)[2];
        float4 f3 = ((const float4*)src)[3];
        const int bb = rr * 256 + q * 32;
        const int sw = (rr & 7) << 4;
        *(uint4*)(xab + (bb ^ sw))        = make_uint4(pk2(f0.x,f0.y), pk2(f0.z,f0.w), pk2(f1.x,f1.y), pk2(f1.z,f1.w));
        *(uint4*)(xab + ((bb + 16) ^ sw)) = make_uint4(pk2(f2.x,f2.y), pk2(f2.z,f2.w), pk2(f3.x,f3.y), pk2(f3.z,f3.w));
    }
    __syncthreads();

    // ---- P4: E/A MFMA -> lds_ea packed {e,a}; wave w: row-tile rt, ci quad (w>>3)*4 ----
    {
        bf16x8 afI[4];
        const int row = rt * 16 + rowl;
        #pragma unroll
        for (int kt = 0; kt < 4; ++kt)
            afI[kt] = *(const bf16x8*)(xab + ((row * 256 + kt * 64 + kb16) ^ ((row & 7) << 4)));
        const int ci0 = (w >> 3) * 4;
        #pragma unroll
        for (int ii = 0; ii < 4; ++ii) {
            const int ci = ci0 + ii;
            f32x4 ae = {0.f,0.f,0.f,0.f}, aa = {0.f,0.f,0.f,0.f};
            #pragma unroll
            for (int kt = 0; kt < 4; ++kt) {
                bf16x8 be = *(const bf16x8*)(Bfrag + ((size_t)(ci * 4 + kt) * 64 + lane) * 8);
                bf16x8 ba = *(const bf16x8*)(Bfrag + ((size_t)((8 + ci) * 4 + kt) * 64 + lane) * 8);
                ae = __builtin_amdgcn_mfma_f32_16x16x32_bf16(afI[kt], be, ae, 0, 0, 0);
                aa = __builtin_amdgcn_mfma_f32_16x16x32_bf16(afI[kt], ba, aa, 0, 0, 0);
            }
            const int cc = ci * 16 + rowl;
            const float bvE = erase_b[cc];
            const float bvA = add_b[cc];
            #pragma unroll
            for (int rr = 0; rr < 4; ++rr) {
                float e = fast_sig(ae[rr] + bvE);
                float a = fast_tanh(aa[rr] + bvA);
                lds_ea[(rt * 16 + rb4 + rr) * VD + cc] = pk2(e, a);
            }
        }
    }

    // scan decomposition: group g = w>>3 (0: steps 0..63 real scan; 1: steps 64..127 transfer)
    const int g  = w >> 3;
    const int w2 = w & 7;
    const int vhalf = w2 & 1;
    const int cq = w2 >> 1;
    const int vg = lane >> 2;
    const int cg = lane & 3;
    const int v0 = vhalf * 64 + vg * 4;
    const int c0 = cq * 16 + cg * 4;

    f32x2 mA[4], mB[4];                // g0: memory state; g1: U (sum part)
    f32x2 DA[4], DB[4];                // g1 only: product part
    if (g == 0) {
        const float* minit = (m == 0) ? rmem0 : wmem0;
        #pragma unroll
        for (int j = 0; j < 4; ++j) {
            float4 mi = *(const float4*)(minit + (v0 + j) * CN + c0);
            mA[j].x = mi.x; mA[j].y = mi.y;
            mB[j].x = mi.z; mB[j].y = mi.w;
        }
    } else {
        #pragma unroll
        for (int j = 0; j < 4; ++j) {
            mA[j].x = 0.f; mA[j].y = 0.f; mB[j].x = 0.f; mB[j].y = 0.f;
            DA[j].x = 1.f; DA[j].y = 1.f; DB[j].x = 1.f; DB[j].y = 1.f;
        }
    }
    __syncthreads();

    // ---- P5: split-s scan (each group: 64 steps, 4v x 4c tile, pk ops) ----
    if (g == 0) {
        for (int so = 0; so < 8; ++so) {
            const unsigned int* eap = lds_ea + (so * 8) * VD + v0;
            const unsigned short* wp = lds_w + (so * 8) * CN + c0;
            #pragma unroll
            for (int kk = 0; kk < 8; ++kk) {
                uint4 ea = *(const uint4*)(eap + kk * VD);
                uint2 wu = *(const uint2*)(wp + kk * CN);
                f32x2 wA; wA.x = bflo(wu.x); wA.y = bfhi(wu.x);
                f32x2 wB; wB.x = bflo(wu.y); wB.y = bfhi(wu.y);
                unsigned int eu[4] = { ea.x, ea.y, ea.z, ea.w };
                #pragma unroll
                for (int j = 0; j < 4; ++j) {
                    float e = bflo(eu[j]), a = bfhi(eu[j]);
                    f32x2 ev; ev.x = e; ev.y = e;
                    f32x2 av; av.x = a; av.y = a;
                    f32x2 gg;
                    gg = pk_nfma(ev, mA[j], av);       // a - e*m
                    mA[j] = pk_fma(wA, gg, mA[j]);     // m + w*g
                    gg = pk_nfma(ev, mB[j], av);
                    mB[j] = pk_fma(wB, gg, mB[j]);
                }
            }
        }
        // publish m_mid into logits region (dead after P3): [v][68] padded
        float* mmid = logits;
        #pragma unroll
        for (int j = 0; j < 4; ++j) {
            float4 f;
            f.x = mA[j].x; f.y = mA[j].y; f.z = mB[j].x; f.w = mB[j].y;
            *(float4*)(mmid + (v0 + j) * 68 + c0) = f;
        }
    } else {
        f32x2 one; one.x = 1.f; one.y = 1.f;
        for (int so = 8; so < 16; ++so) {
            const unsigned int* eap = lds_ea + (so * 8) * VD + v0;
            const unsigned short* wp = lds_w + (so * 8) * CN + c0;
            #pragma unroll
            for (int kk = 0; kk < 8; ++kk) {
                uint4 ea = *(const uint4*)(eap + kk * VD);
                uint2 wu = *(const uint2*)(wp + kk * CN);
                f32x2 wA; wA.x = bflo(wu.x); wA.y = bfhi(wu.x);
                f32x2 wB; wB.x = bflo(wu.y); wB.y = bfhi(wu.y);
                unsigned int eu[4] = { ea.x, ea.y, ea.z, ea.w };
                #pragma unroll
                for (int j = 0; j < 4; ++j) {
                    float e = bflo(eu[j]), a = bfhi(eu[j]);
                    f32x2 ev; ev.x = e; ev.y = e;
                    f32x2 av; av.x = a; av.y = a;
                    f32x2 dA = pk_nfma(ev, wA, one);   // 1 - e*w
                    f32x2 dB = pk_nfma(ev, wB, one);
                    DA[j] = DA[j] * dA;
                    DB[j] = DB[j] * dB;
                    mA[j] = pk_fma(mA[j], dA, av * wA); // U = U*d + a*w
                    mB[j] = pk_fma(mB[j], dB, av * wB);
                }
            }
        }
    }
    __syncthreads();

    // ---- P6 (g1 waves): combine m_final = D*m_mid + U, dot with WT, reduce ----
    if (g == 1) {
        const float* mmid = logits;
        float4 wt = *(const float4*)(wt_lds + c0);
        float p[4];
        #pragma unroll
        for (int j = 0; j < 4; ++j) {
            float4 mi = *(const float4*)(mmid + (v0 + j) * 68 + c0);
            f32x2 miA; miA.x = mi.x; miA.y = mi.y;
            f32x2 miB; miB.x = mi.z; miB.y = mi.w;
            f32x2 fA = pk_fma(DA[j], miA, mA[j]);
            f32x2 fB = pk_fma(DB[j], miB, mB[j]);
            float x = fA.x * wt.x;
            x = fmaf(fA.y, wt.y, x);
            x = fmaf(fB.x, wt.z, x);
            x = fmaf(fB.y, wt.w, x);
            p[j] = x;
        }
        #pragma unroll
        for (int j = 0; j < 4; ++j) {
            p[j] += __shfl_xor(p[j], 1);
            p[j] += __shfl_xor(p[j], 2);
        }
        if (cg == 0) {
            #pragma unroll
            for (int j = 0; j < 4; ++j) psum[w2 * 64 + vg * 4 + j] = p[j];
        }
    }
    __syncthreads();
    if (t < 128) {
        const int vh = t >> 6, vl = t & 63;
        float s = psum[(0 * 2 + vh) * 64 + vl] + psum[(1 * 2 + vh) * 64 + vl]
                + psum[(2 * 2 + vh) * 64 + vl] + psum[(3 * 2 + vh) * 64 + vl];
        readbuf[(size_t)chain * VD + t] = s;
    }
}

// ---------------- kernel 3: head (256 threads, k-split) ----------------
__global__ __launch_bounds__(256) void k_head(
    const float* __restrict__ readbuf, const int* __restrict__ tgt,
    const float* __restrict__ q_emb,
    const float* __restrict__ rsum_W, const float* __restrict__ rsum_b,
    const float* __restrict__ wsum_W, const float* __restrict__ wsum_b,
    const float* __restrict__ succ_W, const float* __restrict__ succ_b,
    const float* __restrict__ fail_W, const float* __restrict__ fail_b,
    const float* __restrict__ diff_W, const float* __restrict__ diff_b,
    const float* __restrict__ sig, float* __restrict__ out)
{
    __shared__ float xr[256], xw[256];
    __shared__ float part[2][128];
    __shared__ float red_s[6];
    const int t = threadIdx.x;
    const int j = t & 127;
    const int h = t >> 7;
    const int b = blockIdx.x;
    if (h == 0) {
        int tid_ = tgt[b];
        float qv = q_emb[(size_t)tid_ * KD + j];
        xr[j]       = readbuf[(size_t)b * VD + j];
        xr[128 + j] = qv;
        xw[j]       = readbuf[(size_t)(BB + b) * VD + j];
        xw[128 + j] = qv;
    }
    __syncthreads();

    float rs = (h == 0) ? rsum_b[j] : 0.0f;
    float wv = (h == 0) ? wsum_b[j] : 0.0f;
    const float* rw = rsum_W + (size_t)j * 256 + h * 128;
    const float* ww = wsum_W + (size_t)j * 256 + h * 128;
    const float* xrp = xr + h * 128;
    const float* xwp = xw + h * 128;
    #pragma unroll 4
    for (int k = 0; k < 128; ++k) {
        rs = fmaf(rw[k], xrp[k], rs);
        wv = fmaf(ww[k], xwp[k], wv);
    }
    if (h == 1) { part[0][j] = rs; part[1][j] = wv; }
    __syncthreads();
    if (h == 0) {
        rs += part[0][j];
        wv += part[1][j];
        float r_sum = fast_tanh(rs), w_sum = fast_tanh(wv);
        float qv = xr[128 + j];
        float ps = r_sum * succ_W[j];
        float pf = w_sum * fail_W[j];
        float pd = qv    * diff_W[j];
        for (int off = 1; off < 64; off <<= 1) {
            ps += __shfl_xor(ps, off);
            pf += __shfl_xor(pf, off);
            pd += __shfl_xor(pd, off);
        }
        int wid = j >> 6;
        if ((j & 63) == 0) { red_s[wid*3+0] = ps; red_s[wid*3+1] = pf; red_s[wid*3+2] = pd; }
    }
    __syncthreads();
    if (t == 0) {
        float Ps = red_s[0] + red_s[3];
        float Pf = red_s[1] + red_s[4];
        float Pd = red_s[2] + red_s[5];
        float succ = fast_tanh(Ps + succ_b[0]);
        float fail = fast_tanh(Pf + fail_b[0]);
        float diff = fast_tanh(Pd + diff_b[0]);
        out[b] = succ * sig[0] + fail * sig[1] - 2.0f * diff;
    }
}

extern "C" void kernel_launch(void* const* d_in, const int* in_sizes, int n_in,
                              void* d_out, int out_size, void* d_ws, size_t ws_size,
                              hipStream_t stream) {
    const int*   ri      = (const int*)d_in[0];
    const int*   wi      = (const int*)d_in[1];
    const int*   tgt     = (const int*)d_in[2];
    const float* q_emb   = (const float*)d_in[3];
    const float* i_emb   = (const float*)d_in[4];
    const float* key_W   = (const float*)d_in[5];
    const float* erase_W = (const float*)d_in[6];
    const float* erase_b = (const float*)d_in[7];
    const float* add_W   = (const float*)d_in[8];
    const float* add_b   = (const float*)d_in[9];
    const float* rsum_W  = (const float*)d_in[10];
    const float* rsum_b  = (const float*)d_in[11];
    const float* wsum_W  = (const float*)d_in[12];
    const float* wsum_b  = (const float*)d_in[13];
    const float* succ_W  = (const float*)d_in[14];
    const float* succ_b  = (const float*)d_in[15];
    const float* fail_W  = (const float*)d_in[16];
    const float* fail_b  = (const float*)d_in[17];
    const float* diff_W  = (const float*)d_in[18];
    const float* diff_b  = (const float*)d_in[19];
    const float* rmem0   = (const float*)d_in[20];
    const float* wmem0   = (const float*)d_in[21];

    char* ws = (char*)d_ws;
    float*          readbuf = (float*)(ws + 0);                   // 131,072 B
    unsigned short* Bfrag   = (unsigned short*)(ws + 131072);     //  81,920 B
    float*          sig     = (float*)(ws + 212992);              //       8 B
    float*          out     = (float*)d_out;

    hipLaunchKernelGGL(k_wcnt, dim3(21), dim3(256), 0, stream,
        erase_W, add_W, key_W, Bfrag, ri, wi, sig);
    hipLaunchKernelGGL(k_chain, dim3(256), dim3(1024), 0, stream,
        ri, wi, tgt, q_emb, i_emb, key_W, erase_b, add_b, Bfrag,
        rmem0, wmem0, readbuf);
    hipLaunchKernelGGL(k_head, dim3(128), dim3(256), 0, stream,
        readbuf, tgt, q_emb, rsum_W, rsum_b, wsum_W, wsum_b,
        succ_W, succ_b, fail_W, fail_b, diff_W, diff_b, sig, out);
}

// Round 13
// 54.526 us; speedup vs baseline: 1.0166x; 1.0166x over previous
//
#include <hip/hip_runtime.h>
#include <hip/hip_bf16.h>

#define BB 128      // batch
#define SS 128      // seq len
#define VD 128      // VALUE_DIM
#define CN 64       // CONCEPT_NUM
#define KD 128      // KEY_DIM
#define QN 10000
#define QSZ (10001 * 128)          // q_emb elems
#define ISZ (20001 * 128)          // i_emb elems
#define TOTE (QSZ + ISZ)           // 3,840,256

typedef __attribute__((ext_vector_type(8))) short bf16x8;
typedef __attribute__((ext_vector_type(4))) float f32x4;
typedef __attribute__((ext_vector_type(2))) float f32x2;

__device__ __forceinline__ float bflo(unsigned int u) { return __uint_as_float(u << 16); }
__device__ __forceinline__ float bfhi(unsigned int u) { return __uint_as_float(u & 0xffff0000u); }
__device__ __forceinline__ unsigned int cvtpk(float lo, float hi) {
    __hip_bfloat162 h2 = __float22bfloat162_rn(make_float2(lo, hi));
    unsigned int r; __builtin_memcpy(&r, &h2, 4); return r;
}
__device__ __forceinline__ float fast_tanh(float x) {
    float e = __expf(2.0f * x);
    return 1.0f - 2.0f / (e + 1.0f);
}
__device__ __forceinline__ float fast_sig(float x) {
    return 1.0f / (1.0f + __expf(-x));
}
// packed dual-f32 FMA: d = a*b + c
__device__ __forceinline__ f32x2 pk_fma(f32x2 a, f32x2 b, f32x2 c) {
    f32x2 d;
    asm("v_pk_fma_f32 %0, %1, %2, %3" : "=v"(d) : "v"(a), "v"(b), "v"(c));
    return d;
}
// d = c - a*b
__device__ __forceinline__ f32x2 pk_nfma(f32x2 a, f32x2 b, f32x2 c) {
    f32x2 d;
    asm("v_pk_fma_f32 %0, %1, %2, %3 neg_lo:[1,0,0] neg_hi:[1,0,0]"
        : "=v"(d) : "v"(a), "v"(b), "v"(c));
    return d;
}

// ---------------- kernel 1: Bfrag pack (0..19) + counts (20) + bf16 table cvt (21..) ----------------
__global__ __launch_bounds__(256) void k_wcnt(
    const float* __restrict__ erase_W, const float* __restrict__ add_W,
    const float* __restrict__ key_W, unsigned short* __restrict__ Bfrag,
    const int* __restrict__ ri, const int* __restrict__ wi, float* __restrict__ sig,
    const float* __restrict__ q_emb, const float* __restrict__ i_emb,
    unsigned short* __restrict__ qbf, unsigned short* __restrict__ ibf)
{
    const int t = threadIdx.x;
    if (blockIdx.x < 20) {
        const int bid = blockIdx.x * 4 + (t >> 6);   // 0..79
        const int l = t & 63;
        const int n = (bid >> 2) * 16 + (l & 15);
        const int k0 = (bid & 3) * 32 + (l >> 4) * 8;
        const float* src;
        if (n < 128)      src = erase_W + (size_t)n * KD + k0;
        else if (n < 256) src = add_W + (size_t)(n - 128) * KD + k0;
        else              src = key_W + (size_t)(n - 256) * KD + k0;
        float4 fa = ((const float4*)src)[0];
        float4 fb = ((const float4*)src)[1];
        uint4 o = make_uint4(cvtpk(fa.x, fa.y), cvtpk(fa.z, fa.w), cvtpk(fb.x, fb.y), cvtpk(fb.z, fb.w));
        *(uint4*)(Bfrag + ((size_t)bid * 64 + l) * 8) = o;
    } else if (blockIdx.x == 20) {
        __shared__ int sr_s[4], sw_s[4];
        const int4* r4 = (const int4*)ri;
        const int4* w4 = (const int4*)wi;
        int sr = 0, sw = 0;
        #pragma unroll 4
        for (int p = 0; p < 16; ++p) {
            int4 a = r4[p * 256 + t];
            int4 b = w4[p * 256 + t];
            sr += (a.x >= 1) + (a.y >= 1) + (a.z >= 1) + (a.w >= 1);
            sw += (b.x >= 1) + (b.y >= 1) + (b.z >= 1) + (b.w >= 1);
        }
        for (int off = 1; off < 64; off <<= 1) { sr += __shfl_xor(sr, off); sw += __shfl_xor(sw, off); }
        int wid = t >> 6;
        if ((t & 63) == 0) { sr_s[wid] = sr; sw_s[wid] = sw; }
        __syncthreads();
        if (t == 0) {
            int SR = sr_s[0]+sr_s[1]+sr_s[2]+sr_s[3];
            int SW = sw_s[0]+sw_s[1]+sw_s[2]+sw_s[3];
            sig[0] = 1.0f / (1.0f + __expf(-(float)SR));
            sig[1] = 1.0f / (1.0f + __expf(-(float)SW));
        }
    } else {
        // bf16 table conversion: 16 elems/thread
        const int idx = (blockIdx.x - 21) * 256 + t;
        const int base = idx * 16;
        if (base < TOTE) {
            const float* src; unsigned short* dst; int off;
            if (base < QSZ) { src = q_emb; dst = qbf; off = base; }
            else            { src = i_emb; dst = ibf; off = base - QSZ; }
            float4 f0 = *(const float4*)(src + off);
            float4 f1 = *(const float4*)(src + off + 4);
            float4 f2 = *(const float4*)(src + off + 8);
            float4 f3 = *(const float4*)(src + off + 12);
            uint4 o0 = make_uint4(cvtpk(f0.x,f0.y), cvtpk(f0.z,f0.w), cvtpk(f1.x,f1.y), cvtpk(f1.z,f1.w));
            uint4 o1 = make_uint4(cvtpk(f2.x,f2.y), cvtpk(f2.z,f2.w), cvtpk(f3.x,f3.y), cvtpk(f3.z,f3.w));
            *(uint4*)(dst + off)     = o0;
            *(uint4*)(dst + off + 8) = o1;
        }
    }
}

// ---------------- kernel 2: fused per-chain {gather -> MFMA E/A/W -> softmax -> scan -> read} ----------------
// grid 256 = chain (m*BB + b); block 512 = 8 waves.
__global__ __launch_bounds__(512, 2) void k_chain(
    const int* __restrict__ ri, const int* __restrict__ wi, const int* __restrict__ tgt,
    const float* __restrict__ q_emb,
    const unsigned short* __restrict__ qbf, const unsigned short* __restrict__ ibf,
    const float* __restrict__ key_W,
    const float* __restrict__ erase_b, const float* __restrict__ add_b,
    const unsigned short* __restrict__ Bfrag,
    const float* __restrict__ rmem0, const float* __restrict__ wmem0,
    float* __restrict__ readbuf)
{
    __shared__ __align__(16) unsigned int lds_ea[SS * VD];    // 64 KB: {e,a} bf16 pair per u32
    __shared__ __align__(16) char xab[32 * 1024];             // 32 KB: Xq, then Xi (bf16, swizzled)
    __shared__ __align__(16) float logits[SS * 68];           // 34816 B
    __shared__ __align__(16) unsigned short lds_w[SS * CN];   // 16 KB: W bf16
    __shared__ float q_t[KD];
    __shared__ float logit_t[CN];
    __shared__ float wt_lds[CN];
    __shared__ int qid_s[SS], ir_s[SS];
    __shared__ float psum[8 * 64];

    const int t = threadIdx.x;
    const int lane = t & 63;
    const int w = t >> 6;
    const int chain = blockIdx.x;
    const int m = chain >> 7;
    const int b = chain & 127;

    // ---- P0: ids + target q row ----
    if (t < SS) {
        int inter = (m == 0 ? ri : wi)[b * SS + t];
        ir_s[t] = inter;
        qid_s[t] = (inter > QN) ? inter - QN : inter;
        q_t[t] = q_emb[(size_t)tgt[b] * KD + t];
    }
    __syncthreads();

    // ---- P1: stage Xq (bf16 direct copy, swizzled) + target-logit partial dots (f32) ----
    {
        const int r0 = t >> 3, o = t & 7;
        #pragma unroll
        for (int h = 0; h < 2; ++h) {
            const int r = r0 + h * 64;
            const uint4* src = (const uint4*)(qbf + (size_t)qid_s[r] * KD) + o * 2;
            uint4 s0 = src[0], s1 = src[1];
            const int bb = r * 256 + o * 32;
            const int sw = (r & 7) << 4;
            *(uint4*)(xab + (bb ^ sw))        = s0;
            *(uint4*)(xab + ((bb + 16) ^ sw)) = s1;
        }
        const int c = t >> 3, oct = t & 7;
        const float* kw = key_W + (size_t)c * KD + oct * 16;
        float s = 0.f;
        #pragma unroll
        for (int i = 0; i < 16; ++i) s = fmaf(kw[i], q_t[oct * 16 + i], s);
        s += __shfl_xor(s, 1); s += __shfl_xor(s, 2); s += __shfl_xor(s, 4);
        if (oct == 0) logit_t[c] = s;
    }
    __syncthreads();

    const int rowl = lane & 15;
    const int kb16 = (lane >> 4) * 16;
    const int rb4 = (lane >> 4) * 4;

    // ---- P2: W-logits MFMA (wave w -> rows w*16..+15, all 4 n-tiles); wave 0 also: target softmax ----
    {
        if (w == 0) {
            float x = logit_t[lane];
            float mx = x;
            #pragma unroll
            for (int off = 1; off < 64; off <<= 1) mx = fmaxf(mx, __shfl_xor(mx, off));
            float e = __expf(x - mx);
            float ssum = e;
            #pragma unroll
            for (int off = 1; off < 64; off <<= 1) ssum += __shfl_xor(ssum, off);
            wt_lds[lane] = e / ssum;
        }
        bf16x8 afQ[4];
        const int row = w * 16 + rowl;
        #pragma unroll
        for (int kt = 0; kt < 4; ++kt)
            afQ[kt] = *(const bf16x8*)(xab + ((row * 256 + kt * 64 + kb16) ^ ((row & 7) << 4)));
        #pragma unroll
        for (int nt = 0; nt < 4; ++nt) {
            f32x4 acc = {0.f,0.f,0.f,0.f};
            #pragma unroll
            for (int kt = 0; kt < 4; ++kt) {
                bf16x8 bf = *(const bf16x8*)(Bfrag + ((size_t)((16 + nt) * 4 + kt) * 64 + lane) * 8);
                acc = __builtin_amdgcn_mfma_f32_16x16x32_bf16(afQ[kt], bf, acc, 0, 0, 0);
            }
            #pragma unroll
            for (int rr = 0; rr < 4; ++rr)
                logits[(w * 16 + rb4 + rr) * 68 + nt * 16 + rowl] = acc[rr];
        }
    }
    __syncthreads();

    // ---- P3: stage Xi (overwrites xab) + softmax-W rows -> lds_w bf16 ----
    {
        const int r0 = t >> 3, o = t & 7;
        uint4 xi[2][2];
        #pragma unroll
        for (int h = 0; h < 2; ++h) {
            const int r = r0 + h * 64;
            const uint4* src = (const uint4*)(ibf + (size_t)ir_s[r] * KD) + o * 2;
            xi[h][0] = src[0];
            xi[h][1] = src[1];
        }

        // softmax over this row's 64 logits: 4 threads/row, 16 cols each
        const int rr = t >> 2, q4 = t & 3;
        const float* L = logits + rr * 68 + q4 * 16;
        float4 va = ((const float4*)L)[0];
        float4 vb = ((const float4*)L)[1];
        float4 vc = ((const float4*)L)[2];
        float4 vd = ((const float4*)L)[3];
        float mx = fmaxf(fmaxf(fmaxf(va.x, va.y), fmaxf(va.z, va.w)),
                         fmaxf(fmaxf(vb.x, vb.y), fmaxf(vb.z, vb.w)));
        mx = fmaxf(mx, fmaxf(fmaxf(fmaxf(vc.x, vc.y), fmaxf(vc.z, vc.w)),
                             fmaxf(fmaxf(vd.x, vd.y), fmaxf(vd.z, vd.w))));
        mx = fmaxf(mx, __shfl_xor(mx, 1));
        mx = fmaxf(mx, __shfl_xor(mx, 2));
        float ex[16];
        ex[0] = __expf(va.x - mx); ex[1] = __expf(va.y - mx); ex[2] = __expf(va.z - mx); ex[3] = __expf(va.w - mx);
        ex[4] = __expf(vb.x - mx); ex[5] = __expf(vb.y - mx); ex[6] = __expf(vb.z - mx); ex[7] = __expf(vb.w - mx);
        ex[8] = __expf(vc.x - mx); ex[9] = __expf(vc.y - mx); ex[10] = __expf(vc.z - mx); ex[11] = __expf(vc.w - mx);
        ex[12] = __expf(vd.x - mx); ex[13] = __expf(vd.y - mx); ex[14] = __expf(vd.z - mx); ex[15] = __expf(vd.w - mx);
        float s = 0.f;
        #pragma unroll
        for (int i = 0; i < 16; ++i) s += ex[i];
        s += __shfl_xor(s, 1);
        s += __shfl_xor(s, 2);
        float inv = 1.0f / s;
        uint4 o0 = make_uint4(cvtpk(ex[0]*inv, ex[1]*inv), cvtpk(ex[2]*inv, ex[3]*inv),
                              cvtpk(ex[4]*inv, ex[5]*inv), cvtpk(ex[6]*inv, ex[7]*inv));
        uint4 o1 = make_uint4(cvtpk(ex[8]*inv, ex[9]*inv), cvtpk(ex[10]*inv, ex[11]*inv),
                              cvtpk(ex[12]*inv, ex[13]*inv), cvtpk(ex[14]*inv, ex[15]*inv));
        *(uint4*)(lds_w + rr * CN + q4 * 16)     = o0;
        *(uint4*)(lds_w + rr * CN + q4 * 16 + 8) = o1;

        // now store Xi into xab (Xq is dead after P2's barrier)
        #pragma unroll
        for (int h = 0; h < 2; ++h) {
            const int r = r0 + h * 64;
            const int bb = r * 256 + o * 32;
            const int sw = (r & 7) << 4;
            *(uint4*)(xab + (bb ^ sw))        = xi[h][0];
            *(uint4*)(xab + ((bb + 16) ^ sw)) = xi[h][1];
        }
    }
    __syncthreads();

    // ---- P4: E/A MFMA (wave w -> rows w*16..+15, 8 col-tile pairs) -> lds_ea packed {e,a} ----
    {
        bf16x8 afI[4];
        const int row = w * 16 + rowl;
        #pragma unroll
        for (int kt = 0; kt < 4; ++kt)
            afI[kt] = *(const bf16x8*)(xab + ((row * 256 + kt * 64 + kb16) ^ ((row & 7) << 4)));
        #pragma unroll
        for (int ci = 0; ci < 8; ++ci) {
            f32x4 ae = {0.f,0.f,0.f,0.f}, aa = {0.f,0.f,0.f,0.f};
            #pragma unroll
            for (int kt = 0; kt < 4; ++kt) {
                bf16x8 be = *(const bf16x8*)(Bfrag + ((size_t)(ci * 4 + kt) * 64 + lane) * 8);
                bf16x8 ba = *(const bf16x8*)(Bfrag + ((size_t)((8 + ci) * 4 + kt) * 64 + lane) * 8);
                ae = __builtin_amdgcn_mfma_f32_16x16x32_bf16(afI[kt], be, ae, 0, 0, 0);
                aa = __builtin_amdgcn_mfma_f32_16x16x32_bf16(afI[kt], ba, aa, 0, 0, 0);
            }
            const int cc = ci * 16 + rowl;
            const float bvE = erase_b[cc];
            const float bvA = add_b[cc];
            #pragma unroll
            for (int rr = 0; rr < 4; ++rr) {
                float e = fast_sig(ae[rr] + bvE);
                float a = fast_tanh(aa[rr] + bvA);
                lds_ea[(w * 16 + rb4 + rr) * VD + cc] = cvtpk(e, a);
            }
        }
    }

    // init memory state while EA writes drain to barrier
    const int vhalf = w & 1;
    const int cq = w >> 1;
    const int vg = lane >> 2;
    const int cg = lane & 3;
    const int v0 = vhalf * 64 + vg * 4;
    const int c0 = cq * 16 + cg * 4;
    const float* minit = (m == 0) ? rmem0 : wmem0;
    f32x2 mA[4], mB[4];
    #pragma unroll
    for (int j = 0; j < 4; ++j) {
        float4 mi = *(const float4*)(minit + (v0 + j) * CN + c0);
        mA[j].x = mi.x; mA[j].y = mi.y;
        mB[j].x = mi.z; mB[j].y = mi.w;
    }
    __syncthreads();

    // ---- P5: scan (4v x 4c per thread, c-pairs via v_pk_fma_f32) ----
    for (int so = 0; so < 16; ++so) {
        const unsigned int* eap = lds_ea + (so * 8) * VD + v0;
        const unsigned short* wp = lds_w + (so * 8) * CN + c0;
        #pragma unroll
        for (int kk = 0; kk < 8; ++kk) {
            uint4 ea = *(const uint4*)(eap + kk * VD);               // ds_read_b128
            uint2 wu = *(const uint2*)(wp + kk * CN);                // ds_read_b64
            f32x2 wA; wA.x = bflo(wu.x); wA.y = bfhi(wu.x);
            f32x2 wB; wB.x = bflo(wu.y); wB.y = bfhi(wu.y);
            unsigned int eu[4] = { ea.x, ea.y, ea.z, ea.w };
            #pragma unroll
            for (int j = 0; j < 4; ++j) {
                float e = bflo(eu[j]), a = bfhi(eu[j]);
                f32x2 ev; ev.x = e; ev.y = e;
                f32x2 av; av.x = a; av.y = a;
                f32x2 g;
                g = pk_nfma(ev, mA[j], av);       // a - e*m
                mA[j] = pk_fma(wA, g, mA[j]);     // m + w*g
                g = pk_nfma(ev, mB[j], av);
                mB[j] = pk_fma(wB, g, mB[j]);
            }
        }
    }

    // ---- P6: read epilogue with in-block f32 WT ----
    {
        float4 wt = *(const float4*)(wt_lds + c0);
        float p[4];
        #pragma unroll
        for (int j = 0; j < 4; ++j) {
            float x = mA[j].x * wt.x;
            x = fmaf(mA[j].y, wt.y, x);
            x = fmaf(mB[j].x, wt.z, x);
            x = fmaf(mB[j].y, wt.w, x);
            p[j] = x;
        }
        #pragma unroll
        for (int j = 0; j < 4; ++j) {
            p[j] += __shfl_xor(p[j], 1);
            p[j] += __shfl_xor(p[j], 2);
        }
        if (cg == 0) {
            #pragma unroll
            for (int j = 0; j < 4; ++j) psum[w * 64 + vg * 4 + j] = p[j];
        }
    }
    __syncthreads();
    if (t < 128) {
        const int vh = t >> 6, vl = t & 63;
        float s = psum[(0 * 2 + vh) * 64 + vl] + psum[(1 * 2 + vh) * 64 + vl]
                + psum[(2 * 2 + vh) * 64 + vl] + psum[(3 * 2 + vh) * 64 + vl];
        readbuf[(size_t)chain * VD + t] = s;
    }
}

// ---------------- kernel 3: head (256 threads, k-split) ----------------
__global__ __launch_bounds__(256) void k_head(
    const float* __restrict__ readbuf, const int* __restrict__ tgt,
    const float* __restrict__ q_emb,
    const float* __restrict__ rsum_W, const float* __restrict__ rsum_b,
    const float* __restrict__ wsum_W, const float* __restrict__ wsum_b,
    const float* __restrict__ succ_W, const float* __restrict__ succ_b,
    const float* __restrict__ fail_W, const float* __restrict__ fail_b,
    const float* __restrict__ diff_W, const float* __restrict__ diff_b,
    const float* __restrict__ sig, float* __restrict__ out)
{
    __shared__ float xr[256], xw[256];
    __shared__ float part[2][128];
    __shared__ float red_s[6];
    const int t = threadIdx.x;
    const int j = t & 127;
    const int h = t >> 7;
    const int b = blockIdx.x;
    if (h == 0) {
        int tid_ = tgt[b];
        float qv = q_emb[(size_t)tid_ * KD + j];
        xr[j]       = readbuf[(size_t)b * VD + j];
        xr[128 + j] = qv;
        xw[j]       = readbuf[(size_t)(BB + b) * VD + j];
        xw[128 + j] = qv;
    }
    __syncthreads();

    float rs = (h == 0) ? rsum_b[j] : 0.0f;
    float wv = (h == 0) ? wsum_b[j] : 0.0f;
    const float* rw = rsum_W + (size_t)j * 256 + h * 128;
    const float* ww = wsum_W + (size_t)j * 256 + h * 128;
    const float* xrp = xr + h * 128;
    const float* xwp = xw + h * 128;
    #pragma unroll 4
    for (int k = 0; k < 128; ++k) {
        rs = fmaf(rw[k], xrp[k], rs);
        wv = fmaf(ww[k], xwp[k], wv);
    }
    if (h == 1) { part[0][j] = rs; part[1][j] = wv; }
    __syncthreads();
    if (h == 0) {
        rs += part[0][j];
        wv += part[1][j];
        float r_sum = fast_tanh(rs), w_sum = fast_tanh(wv);
        float qv = xr[128 + j];
        float ps = r_sum * succ_W[j];
        float pf = w_sum * fail_W[j];
        float pd = qv    * diff_W[j];
        for (int off = 1; off < 64; off <<= 1) {
            ps += __shfl_xor(ps, off);
            pf += __shfl_xor(pf, off);
            pd += __shfl_xor(pd, off);
        }
        int wid = j >> 6;
        if ((j & 63) == 0) { red_s[wid*3+0] = ps; red_s[wid*3+1] = pf; red_s[wid*3+2] = pd; }
    }
    __syncthreads();
    if (t == 0) {
        float Ps = red_s[0] + red_s[3];
        float Pf = red_s[1] + red_s[4];
        float Pd = red_s[2] + red_s[5];
        float succ = fast_tanh(Ps + succ_b[0]);
        float fail = fast_tanh(Pf + fail_b[0]);
        float diff = fast_tanh(Pd + diff_b[0]);
        out[b] = succ * sig[0] + fail * sig[1] - 2.0f * diff;
    }
}

extern "C" void kernel_launch(void* const* d_in, const int* in_sizes, int n_in,
                              void* d_out, int out_size, void* d_ws, size_t ws_size,
                              hipStream_t stream) {
    const int*   ri      = (const int*)d_in[0];
    const int*   wi      = (const int*)d_in[1];
    const int*   tgt     = (const int*)d_in[2];
    const float* q_emb   = (const float*)d_in[3];
    const float* i_emb   = (const float*)d_in[4];
    const float* key_W   = (const float*)d_in[5];
    const float* erase_W = (const float*)d_in[6];
    const float* erase_b = (const float*)d_in[7];
    const float* add_W   = (const float*)d_in[8];
    const float* add_b   = (const float*)d_in[9];
    const float* rsum_W  = (const float*)d_in[10];
    const float* rsum_b  = (const float*)d_in[11];
    const float* wsum_W  = (const float*)d_in[12];
    const float* wsum_b  = (const float*)d_in[13];
    const float* succ_W  = (const float*)d_in[14];
    const float* succ_b  = (const float*)d_in[15];
    const float* fail_W  = (const float*)d_in[16];
    const float* fail_b  = (const float*)d_in[17];
    const float* diff_W  = (const float*)d_in[18];
    const float* diff_b  = (const float*)d_in[19];
    const float* rmem0   = (const float*)d_in[20];
    const float* wmem0   = (const float*)d_in[21];

    char* ws = (char*)d_ws;
    float*          readbuf = (float*)(ws + 0);                   // 131,072 B
    unsigned short* Bfrag   = (unsigned short*)(ws + 131072);     //  81,920 B
    float*          sig     = (float*)(ws + 212992);              //       8 B
    unsigned short* qbf     = (unsigned short*)(ws + 213504);     // 2,560,256 B
    unsigned short* ibf     = (unsigned short*)(ws + 2773760);    // 5,120,256 B (ends 7,894,016)
    float*          out     = (float*)d_out;

    // 21 setup blocks + ceil(TOTE/16/256) = 938 conversion blocks
    hipLaunchKernelGGL(k_wcnt, dim3(959), dim3(256), 0, stream,
        erase_W, add_W, key_W, Bfrag, ri, wi, sig, q_emb, i_emb, qbf, ibf);
    hipLaunchKernelGGL(k_chain, dim3(256), dim3(512), 0, stream,
        ri, wi, tgt, q_emb, qbf, ibf, key_W, erase_b, add_b, Bfrag,
        rmem0, wmem0, readbuf);
    hipLaunchKernelGGL(k_head, dim3(128), dim3(256), 0, stream,
        readbuf, tgt, q_emb, rsum_W, rsum_b, wsum_W, wsum_b,
        succ_W, succ_b, fail_W, fail_b, diff_W, diff_b, sig, out);
}

// Round 14
// 50.143 us; speedup vs baseline: 1.1055x; 1.0874x over previous
//
#include <hip/hip_runtime.h>
#include <hip/hip_bf16.h>

#define BB 128      // batch
#define SS 128      // seq len
#define VD 128      // VALUE_DIM
#define CN 64       // CONCEPT_NUM
#define KD 128      // KEY_DIM
#define QN 10000

typedef __attribute__((ext_vector_type(8))) short bf16x8;
typedef __attribute__((ext_vector_type(4))) float f32x4;

__device__ __forceinline__ float bflo(unsigned int u) { return __uint_as_float(u << 16); }
__device__ __forceinline__ float bfhi(unsigned int u) { return __uint_as_float(u & 0xffff0000u); }
__device__ __forceinline__ unsigned int cvtpk(float lo, float hi) {
    __hip_bfloat162 h2 = __float22bfloat162_rn(make_float2(lo, hi));
    unsigned int r; __builtin_memcpy(&r, &h2, 4); return r;
}
__device__ __forceinline__ float fast_tanh(float x) {
    float e = __expf(2.0f * x);
    return 1.0f - 2.0f / (e + 1.0f);
}
__device__ __forceinline__ float fast_sig(float x) {
    return 1.0f / (1.0f + __expf(-x));
}

// ---------------- kernel 1: weight pack (blocks 0..19) + counts (block 20) ----------------
__global__ __launch_bounds__(256) void k_wcnt(
    const float* __restrict__ erase_W, const float* __restrict__ add_W,
    const float* __restrict__ key_W, unsigned short* __restrict__ Bfrag,
    const int* __restrict__ ri, const int* __restrict__ wi, float* __restrict__ sig)
{
    const int t = threadIdx.x;
    if (blockIdx.x < 20) {
        const int bid = blockIdx.x * 4 + (t >> 6);   // 0..79
        const int l = t & 63;
        const int n = (bid >> 2) * 16 + (l & 15);
        const int k0 = (bid & 3) * 32 + (l >> 4) * 8;
        const float* src;
        if (n < 128)      src = erase_W + (size_t)n * KD + k0;
        else if (n < 256) src = add_W + (size_t)(n - 128) * KD + k0;
        else              src = key_W + (size_t)(n - 256) * KD + k0;
        float4 fa = ((const float4*)src)[0];
        float4 fb = ((const float4*)src)[1];
        uint4 o = make_uint4(cvtpk(fa.x, fa.y), cvtpk(fa.z, fa.w), cvtpk(fb.x, fb.y), cvtpk(fb.z, fb.w));
        *(uint4*)(Bfrag + ((size_t)bid * 64 + l) * 8) = o;
    } else {
        __shared__ int sr_s[4], sw_s[4];
        const int4* r4 = (const int4*)ri;
        const int4* w4 = (const int4*)wi;
        int sr = 0, sw = 0;
        #pragma unroll 4
        for (int p = 0; p < 16; ++p) {
            int4 a = r4[p * 256 + t];
            int4 b = w4[p * 256 + t];
            sr += (a.x >= 1) + (a.y >= 1) + (a.z >= 1) + (a.w >= 1);
            sw += (b.x >= 1) + (b.y >= 1) + (b.z >= 1) + (b.w >= 1);
        }
        for (int off = 1; off < 64; off <<= 1) { sr += __shfl_xor(sr, off); sw += __shfl_xor(sw, off); }
        int wid = t >> 6;
        if ((t & 63) == 0) { sr_s[wid] = sr; sw_s[wid] = sw; }
        __syncthreads();
        if (t == 0) {
            int SR = sr_s[0]+sr_s[1]+sr_s[2]+sr_s[3];
            int SW = sw_s[0]+sw_s[1]+sw_s[2]+sw_s[3];
            sig[0] = 1.0f / (1.0f + __expf(-(float)SR));
            sig[1] = 1.0f / (1.0f + __expf(-(float)SW));
        }
    }
}

// ---------------- kernel 2: fused per-chain; 16-wave front + 8-wave scan ----------------
// grid 256 = chain (m*BB + b); block 1024 = 16 waves.
__global__ __launch_bounds__(1024, 4) void k_chain(
    const int* __restrict__ ri, const int* __restrict__ wi, const int* __restrict__ tgt,
    const float* __restrict__ q_emb, const float* __restrict__ i_emb,
    const float* __restrict__ key_W,
    const float* __restrict__ erase_b, const float* __restrict__ add_b,
    const unsigned short* __restrict__ Bfrag,
    const float* __restrict__ rmem0, const float* __restrict__ wmem0,
    float* __restrict__ readbuf)
{
    __shared__ __align__(16) unsigned int lds_ea[SS * VD];    // 64 KB: {e,a} bf16 pair per u32
    __shared__ __align__(16) char xab[32 * 1024];             // 32 KB: Xq, then Xi (bf16, swizzled)
    __shared__ __align__(16) float logits[SS * 68];           // 34816 B
    __shared__ __align__(16) unsigned short lds_w[SS * CN];   // 16 KB: W bf16
    __shared__ float q_t[KD];
    __shared__ float logit_t[CN];
    __shared__ float wt_lds[CN];
    __shared__ int qid_s[SS], ir_s[SS];
    __shared__ float psum[8 * 64];

    const int t = threadIdx.x;
    const int lane = t & 63;
    const int w = t >> 6;              // 0..15
    const int chain = blockIdx.x;
    const int m = chain >> 7;
    const int b = chain & 127;

    // ---- P0: ids + target q row ----
    if (t < SS) {
        int inter = (m == 0 ? ri : wi)[b * SS + t];
        ir_s[t] = inter;
        qid_s[t] = (inter > QN) ? inter - QN : inter;
        q_t[t] = q_emb[(size_t)tgt[b] * KD + t];
    }
    __syncthreads();

    // ---- P1: stage Xq (one row-half per thread) + target-logit partial dots ----
    {
        const int r = t >> 3, o = t & 7;
        const float* src = q_emb + (size_t)qid_s[r] * KD + o * 16;
        float4 f0 = ((const float4*)src)[0];
        float4 f1 = ((const float4*)src)[1];
        float4 f2 = ((const float4*)src)[2];
        float4 f3 = ((const float4*)src)[3];
        const int bb = r * 256 + o * 32;
        const int sw = (r & 7) << 4;
        *(uint4*)(xab + (bb ^ sw))        = make_uint4(cvtpk(f0.x,f0.y), cvtpk(f0.z,f0.w), cvtpk(f1.x,f1.y), cvtpk(f1.z,f1.w));
        *(uint4*)(xab + ((bb + 16) ^ sw)) = make_uint4(cvtpk(f2.x,f2.y), cvtpk(f2.z,f2.w), cvtpk(f3.x,f3.y), cvtpk(f3.z,f3.w));
        if (t < 512) {
            const int c = t >> 3, oct = t & 7;
            const float* kw = key_W + (size_t)c * KD + oct * 16;
            float s = 0.f;
            #pragma unroll
            for (int i = 0; i < 16; ++i) s = fmaf(kw[i], q_t[oct * 16 + i], s);
            s += __shfl_xor(s, 1); s += __shfl_xor(s, 2); s += __shfl_xor(s, 4);
            if (oct == 0) logit_t[c] = s;
        }
    }
    __syncthreads();

    const int rowl = lane & 15;
    const int kb16 = (lane >> 4) * 16;
    const int rb4 = (lane >> 4) * 4;
    const int rt = w & 7;              // row-tile 0..7

    // ---- P2: W-logits MFMA (wave w: row-tile rt, nt pair (w>>3)*2); wave 0: target softmax ----
    {
        if (w == 0) {
            float x = logit_t[lane];
            float mx = x;
            #pragma unroll
            for (int off = 1; off < 64; off <<= 1) mx = fmaxf(mx, __shfl_xor(mx, off));
            float e = __expf(x - mx);
            float ssum = e;
            #pragma unroll
            for (int off = 1; off < 64; off <<= 1) ssum += __shfl_xor(ssum, off);
            wt_lds[lane] = e / ssum;
        }
        bf16x8 afQ[4];
        const int row = rt * 16 + rowl;
        #pragma unroll
        for (int kt = 0; kt < 4; ++kt)
            afQ[kt] = *(const bf16x8*)(xab + ((row * 256 + kt * 64 + kb16) ^ ((row & 7) << 4)));
        const int nt0 = (w >> 3) * 2;
        #pragma unroll
        for (int ni = 0; ni < 2; ++ni) {
            const int nt = nt0 + ni;
            f32x4 acc = {0.f,0.f,0.f,0.f};
            #pragma unroll
            for (int kt = 0; kt < 4; ++kt) {
                bf16x8 bf = *(const bf16x8*)(Bfrag + ((size_t)((16 + nt) * 4 + kt) * 64 + lane) * 8);
                acc = __builtin_amdgcn_mfma_f32_16x16x32_bf16(afQ[kt], bf, acc, 0, 0, 0);
            }
            #pragma unroll
            for (int rr = 0; rr < 4; ++rr)
                logits[(rt * 16 + rb4 + rr) * 68 + nt * 16 + rowl] = acc[rr];
        }
    }
    __syncthreads();

    // ---- P3: softmax rows -> lds_w (8 thr/row) + stage Xi into xab ----
    {
        const int rr = t >> 3, q = t & 7;
        const float* L = logits + rr * 68 + q * 8;
        float4 va = ((const float4*)L)[0];
        float4 vb = ((const float4*)L)[1];
        float mx = fmaxf(fmaxf(fmaxf(va.x, va.y), fmaxf(va.z, va.w)),
                         fmaxf(fmaxf(vb.x, vb.y), fmaxf(vb.z, vb.w)));
        mx = fmaxf(mx, __shfl_xor(mx, 1));
        mx = fmaxf(mx, __shfl_xor(mx, 2));
        mx = fmaxf(mx, __shfl_xor(mx, 4));
        float e0 = __expf(va.x - mx), e1 = __expf(va.y - mx), e2 = __expf(va.z - mx), e3 = __expf(va.w - mx);
        float e4 = __expf(vb.x - mx), e5 = __expf(vb.y - mx), e6 = __expf(vb.z - mx), e7 = __expf(vb.w - mx);
        float s = e0 + e1 + e2 + e3 + e4 + e5 + e6 + e7;
        s += __shfl_xor(s, 1); s += __shfl_xor(s, 2); s += __shfl_xor(s, 4);
        float inv = 1.0f / s;
        uint4 o = make_uint4(cvtpk(e0*inv, e1*inv), cvtpk(e2*inv, e3*inv),
                             cvtpk(e4*inv, e5*inv), cvtpk(e6*inv, e7*inv));
        *(uint4*)(lds_w + rr * CN + q * 8) = o;

        // Xi gather (Xq in xab dead after P2's barrier)
        const float* src = i_emb + (size_t)ir_s[rr] * KD + q * 16;
        float4 f0 = ((const float4*)src)[0];
        float4 f1 = ((const float4*)src)[1];
        float4 f2 = ((const float4*)src)[2];
        float4 f3 = ((const float4*)src)[3];
        const int bb = rr * 256 + q * 32;
        const int sw = (rr & 7) << 4;
        *(uint4*)(xab + (bb ^ sw))        = make_uint4(cvtpk(f0.x,f0.y), cvtpk(f0.z,f0.w), cvtpk(f1.x,f1.y), cvtpk(f1.z,f1.w));
        *(uint4*)(xab + ((bb + 16) ^ sw)) = make_uint4(cvtpk(f2.x,f2.y), cvtpk(f2.z,f2.w), cvtpk(f3.x,f3.y), cvtpk(f3.z,f3.w));
    }
    __syncthreads();

    // ---- P4: E/A MFMA -> lds_ea packed {e,a}; wave w: row-tile rt, ci quad (w>>3)*4 ----
    {
        bf16x8 afI[4];
        const int row = rt * 16 + rowl;
        #pragma unroll
        for (int kt = 0; kt < 4; ++kt)
            afI[kt] = *(const bf16x8*)(xab + ((row * 256 + kt * 64 + kb16) ^ ((row & 7) << 4)));
        const int ci0 = (w >> 3) * 4;
        #pragma unroll
        for (int ii = 0; ii < 4; ++ii) {
            const int ci = ci0 + ii;
            f32x4 ae = {0.f,0.f,0.f,0.f}, aa = {0.f,0.f,0.f,0.f};
            #pragma unroll
            for (int kt = 0; kt < 4; ++kt) {
                bf16x8 be = *(const bf16x8*)(Bfrag + ((size_t)(ci * 4 + kt) * 64 + lane) * 8);
                bf16x8 ba = *(const bf16x8*)(Bfrag + ((size_t)((8 + ci) * 4 + kt) * 64 + lane) * 8);
                ae = __builtin_amdgcn_mfma_f32_16x16x32_bf16(afI[kt], be, ae, 0, 0, 0);
                aa = __builtin_amdgcn_mfma_f32_16x16x32_bf16(afI[kt], ba, aa, 0, 0, 0);
            }
            const int cc = ci * 16 + rowl;
            const float bvE = erase_b[cc];
            const float bvA = add_b[cc];
            #pragma unroll
            for (int rr = 0; rr < 4; ++rr) {
                float e = fast_sig(ae[rr] + bvE);
                float a = fast_tanh(aa[rr] + bvA);
                lds_ea[(rt * 16 + rb4 + rr) * VD + cc] = cvtpk(e, a);
            }
        }
    }

    // scan thread mapping (threads t<512 only; same as R9)
    const int w2 = w & 7;
    const int vhalf = w2 & 1;
    const int cq = w2 >> 1;
    const int vg = lane >> 2;
    const int cg = lane & 3;
    const int v0 = vhalf * 64 + vg * 4;
    const int c0 = cq * 16 + cg * 4;

    float mm[4][4];
    if (t < 512) {
        const float* minit = (m == 0) ? rmem0 : wmem0;
        #pragma unroll
        for (int j = 0; j < 4; ++j) {
            float4 mi = *(const float4*)(minit + (v0 + j) * CN + c0);
            mm[j][0] = mi.x; mm[j][1] = mi.y; mm[j][2] = mi.z; mm[j][3] = mi.w;
        }
    }
    __syncthreads();

    // ---- P5: scan (t<512: 4v x 4c register tile, scalar fmaf) ----
    if (t < 512) {
        for (int so = 0; so < 16; ++so) {
            const unsigned int* eap = lds_ea + (so * 8) * VD + v0;
            const unsigned short* wp = lds_w + (so * 8) * CN + c0;
            #pragma unroll
            for (int kk = 0; kk < 8; ++kk) {
                uint4 ea = *(const uint4*)(eap + kk * VD);               // ds_read_b128
                uint2 wu = *(const uint2*)(wp + kk * CN);                // ds_read_b64
                float e[4] = { bflo(ea.x), bflo(ea.y), bflo(ea.z), bflo(ea.w) };
                float a[4] = { bfhi(ea.x), bfhi(ea.y), bfhi(ea.z), bfhi(ea.w) };
                float wv[4] = { bflo(wu.x), bfhi(wu.x), bflo(wu.y), bfhi(wu.y) };
                #pragma unroll
                for (int j = 0; j < 4; ++j) {
                    #pragma unroll
                    for (int k = 0; k < 4; ++k) {
                        float g = fmaf(-e[j], mm[j][k], a[j]);   // a - e*m
                        mm[j][k] = fmaf(wv[k], g, mm[j][k]);     // m + w*(a - e*m)
                    }
                }
            }
        }

        // ---- P6: read epilogue with in-block f32 WT ----
        float4 wt = *(const float4*)(wt_lds + c0);
        float p[4];
        #pragma unroll
        for (int j = 0; j < 4; ++j) {
            float x = mm[j][0] * wt.x;
            x = fmaf(mm[j][1], wt.y, x);
            x = fmaf(mm[j][2], wt.z, x);
            x = fmaf(mm[j][3], wt.w, x);
            p[j] = x;
        }
        #pragma unroll
        for (int j = 0; j < 4; ++j) {
            p[j] += __shfl_xor(p[j], 1);
            p[j] += __shfl_xor(p[j], 2);
        }
        if (cg == 0) {
            #pragma unroll
            for (int j = 0; j < 4; ++j) psum[w2 * 64 + vg * 4 + j] = p[j];
        }
    }
    __syncthreads();
    if (t < 128) {
        const int vh = t >> 6, vl = t & 63;
        float s = psum[(0 * 2 + vh) * 64 + vl] + psum[(1 * 2 + vh) * 64 + vl]
                + psum[(2 * 2 + vh) * 64 + vl] + psum[(3 * 2 + vh) * 64 + vl];
        readbuf[(size_t)chain * VD + t] = s;
    }
}

// ---------------- kernel 3: head (256 threads, k-split) ----------------
__global__ __launch_bounds__(256) void k_head(
    const float* __restrict__ readbuf, const int* __restrict__ tgt,
    const float* __restrict__ q_emb,
    const float* __restrict__ rsum_W, const float* __restrict__ rsum_b,
    const float* __restrict__ wsum_W, const float* __restrict__ wsum_b,
    const float* __restrict__ succ_W, const float* __restrict__ succ_b,
    const float* __restrict__ fail_W, const float* __restrict__ fail_b,
    const float* __restrict__ diff_W, const float* __restrict__ diff_b,
    const float* __restrict__ sig, float* __restrict__ out)
{
    __shared__ float xr[256], xw[256];
    __shared__ float part[2][128];
    __shared__ float red_s[6];
    const int t = threadIdx.x;
    const int j = t & 127;
    const int h = t >> 7;
    const int b = blockIdx.x;
    if (h == 0) {
        int tid_ = tgt[b];
        float qv = q_emb[(size_t)tid_ * KD + j];
        xr[j]       = readbuf[(size_t)b * VD + j];
        xr[128 + j] = qv;
        xw[j]       = readbuf[(size_t)(BB + b) * VD + j];
        xw[128 + j] = qv;
    }
    __syncthreads();

    float rs = (h == 0) ? rsum_b[j] : 0.0f;
    float wv = (h == 0) ? wsum_b[j] : 0.0f;
    const float* rw = rsum_W + (size_t)j * 256 + h * 128;
    const float* ww = wsum_W + (size_t)j * 256 + h * 128;
    const float* xrp = xr + h * 128;
    const float* xwp = xw + h * 128;
    #pragma unroll 4
    for (int k = 0; k < 128; ++k) {
        rs = fmaf(rw[k], xrp[k], rs);
        wv = fmaf(ww[k], xwp[k], wv);
    }
    if (h == 1) { part[0][j] = rs; part[1][j] = wv; }
    __syncthreads();
    if (h == 0) {
        rs += part[0][j];
        wv += part[1][j];
        float r_sum = fast_tanh(rs), w_sum = fast_tanh(wv);
        float qv = xr[128 + j];
        float ps = r_sum * succ_W[j];
        float pf = w_sum * fail_W[j];
        float pd = qv    * diff_W[j];
        for (int off = 1; off < 64; off <<= 1) {
            ps += __shfl_xor(ps, off);
            pf += __shfl_xor(pf, off);
            pd += __shfl_xor(pd, off);
        }
        int wid = j >> 6;
        if ((j & 63) == 0) { red_s[wid*3+0] = ps; red_s[wid*3+1] = pf; red_s[wid*3+2] = pd; }
    }
    __syncthreads();
    if (t == 0) {
        float Ps = red_s[0] + red_s[3];
        float Pf = red_s[1] + red_s[4];
        float Pd = red_s[2] + red_s[5];
        float succ = fast_tanh(Ps + succ_b[0]);
        float fail = fast_tanh(Pf + fail_b[0]);
        float diff = fast_tanh(Pd + diff_b[0]);
        out[b] = succ * sig[0] + fail * sig[1] - 2.0f * diff;
    }
}

extern "C" void kernel_launch(void* const* d_in, const int* in_sizes, int n_in,
                              void* d_out, int out_size, void* d_ws, size_t ws_size,
                              hipStream_t stream) {
    const int*   ri      = (const int*)d_in[0];
    const int*   wi      = (const int*)d_in[1];
    const int*   tgt     = (const int*)d_in[2];
    const float* q_emb   = (const float*)d_in[3];
    const float* i_emb   = (const float*)d_in[4];
    const float* key_W   = (const float*)d_in[5];
    const float* erase_W = (const float*)d_in[6];
    const float* erase_b = (const float*)d_in[7];
    const float* add_W   = (const float*)d_in[8];
    const float* add_b   = (const float*)d_in[9];
    const float* rsum_W  = (const float*)d_in[10];
    const float* rsum_b  = (const float*)d_in[11];
    const float* wsum_W  = (const float*)d_in[12];
    const float* wsum_b  = (const float*)d_in[13];
    const float* succ_W  = (const float*)d_in[14];
    const float* succ_b  = (const float*)d_in[15];
    const float* fail_W  = (const float*)d_in[16];
    const float* fail_b  = (const float*)d_in[17];
    const float* diff_W  = (const float*)d_in[18];
    const float* diff_b  = (const float*)d_in[19];
    const float* rmem0   = (const float*)d_in[20];
    const float* wmem0   = (const float*)d_in[21];

    char* ws = (char*)d_ws;
    float*          readbuf = (float*)(ws + 0);                   // 131,072 B
    unsigned short* Bfrag   = (unsigned short*)(ws + 131072);     //  81,920 B
    float*          sig     = (float*)(ws + 212992);              //       8 B
    float*          out     = (float*)d_out;

    hipLaunchKernelGGL(k_wcnt, dim3(21), dim3(256), 0, stream,
        erase_W, add_W, key_W, Bfrag, ri, wi, sig);
    hipLaunchKernelGGL(k_chain, dim3(256), dim3(1024), 0, stream,
        ri, wi, tgt, q_emb, i_emb, key_W, erase_b, add_b, Bfrag,
        rmem0, wmem0, readbuf);
    hipLaunchKernelGGL(k_head, dim3(128), dim3(256), 0, stream,
        readbuf, tgt, q_emb, rsum_W, rsum_b, wsum_W, wsum_b,
        succ_W, succ_b, fail_W, fail_b, diff_W, diff_b, sig, out);
}